// Round 8
// baseline (446.118 us; speedup 1.0000x reference)
//
#include <hip/hip_runtime.h>
#include <hip/hip_cooperative_groups.h>
#include <hip/hip_bf16.h>
#include <stdint.h>

namespace cg = cooperative_groups;

#define NE    8
#define NTOK  1024
#define NH    1024
#define NI    1024
#define N13   2048
#define NPAIR 2048

#define P0_ITEMS 7169   // 1 routing + 512 Xcvt + 512 zero-out + 6144 Wcvt tiles
#define G1MAX    736    // (2048/128 + 7) * (1024/32)
#define G2MAX    624    // (2048/64  + 7) * (1024/64)

typedef __attribute__((ext_vector_type(8))) short short8;
typedef __attribute__((ext_vector_type(4))) float f32x4;
typedef unsigned short u16;
typedef unsigned int   u32;

__device__ __forceinline__ u16 f2bf(float x) {
    union { float f; u32 u; } v; v.f = x;
    return (u16)((v.u + 0x7fffu + ((v.u >> 16) & 1u)) >> 16);
}

__device__ __forceinline__ void async_ld16(u16* lds, const u16* g) {
    __builtin_amdgcn_global_load_lds(
        (const __attribute__((address_space(1))) u32*)g,
        (__attribute__((address_space(3))) u32*)lds, 16, 0, 0);
}

__device__ __forceinline__ bool find_tile(
    const int* __restrict__ counts, int tile, int bm, int ntn,
    int& e_o, int& mt_o, int& nt_o, int& cnt_o, int& base_o)
{
    int base = 0;
    #pragma unroll
    for (int e = 0; e < NE; e++) {
        const int cnt = counts[e];
        const int mtiles = (cnt + bm - 1) / bm;
        const int tiles = mtiles * ntn;
        if (tile < tiles) {
            e_o = e; mt_o = tile / ntn; nt_o = tile - (tile / ntn) * ntn;
            cnt_o = cnt; base_o = base; return true;
        }
        tile -= tiles; base += cnt;
    }
    return false;
}

// ===========================================================================
// Phase 0 work item: 0 = routing; 1..512 = X cvt; 513..1024 = zero out;
// 1025..7168 = weight transpose+cvt tiles (4096 W13 + 2048 W2)
// ===========================================================================
__device__ __forceinline__ void phase0_item(
    int b, char* smem,
    const float* __restrict__ X, const float* __restrict__ logits,
    const float* __restrict__ W13, const float* __restrict__ W2,
    float* __restrict__ out, int* __restrict__ counts,
    int* __restrict__ pair_tok, float* __restrict__ pair_w,
    u16* __restrict__ Xb, u16* __restrict__ W13t, u16* __restrict__ W2t)
{
    const int tid = threadIdx.x;
    if (b == 0) {
        int* s_cnt  = (int*)smem;
        int* s_base = s_cnt + NE;
        if (tid < NE) s_cnt[tid] = 0;
        __syncthreads();
        int eA[4][2]; int slotA[4][2]; float wA[4][2];
        #pragma unroll
        for (int i = 0; i < 4; i++) {
            const int t = tid * 4 + i;
            float l[NE];
            #pragma unroll
            for (int e = 0; e < NE; e++) l[e] = logits[t * NE + e];
            int i0 = 0;
            #pragma unroll
            for (int e = 1; e < NE; e++) if (l[e] > l[i0]) i0 = e;
            int i1 = -1;
            #pragma unroll
            for (int e = 0; e < NE; e++) {
                if (e == i0) continue;
                if (i1 < 0 || l[e] > l[i1]) i1 = e;
            }
            const float e10 = __expf(l[i1] - l[i0]);
            const float inv = 1.0f / (1.0f + e10);
            eA[i][0] = i0; eA[i][1] = i1;
            wA[i][0] = inv; wA[i][1] = e10 * inv;
            slotA[i][0] = atomicAdd(&s_cnt[i0], 1);
            slotA[i][1] = atomicAdd(&s_cnt[i1], 1);
        }
        __syncthreads();
        if (tid == 0) {
            int acc = 0;
            #pragma unroll
            for (int e = 0; e < NE; e++) { s_base[e] = acc; acc += s_cnt[e]; }
        }
        __syncthreads();
        if (tid < NE) counts[tid] = s_cnt[tid];
        #pragma unroll
        for (int i = 0; i < 4; i++) {
            const int t = tid * 4 + i;
            #pragma unroll
            for (int k = 0; k < 2; k++) {
                const int p = s_base[eA[i][k]] + slotA[i][k];
                pair_tok[p] = t;
                pair_w[p]   = wA[i][k];
            }
        }
    } else if (b <= 512) {
        const int i = (b - 1) * 256 + tid;
        const float4* s = (const float4*)X;
        const float4 a = s[2 * i], c = s[2 * i + 1];
        uint4 o;
        o.x = f2bf(a.x) | ((u32)f2bf(a.y) << 16);
        o.y = f2bf(a.z) | ((u32)f2bf(a.w) << 16);
        o.z = f2bf(c.x) | ((u32)f2bf(c.y) << 16);
        o.w = f2bf(c.z) | ((u32)f2bf(c.w) << 16);
        *(uint4*)(Xb + (size_t)i * 8) = o;
    } else if (b <= 1024) {
        const int i = ((b - 513) * 256 + tid) * 8;
        const float4 z = make_float4(0.f, 0.f, 0.f, 0.f);
        *(float4*)(out + i)     = z;
        *(float4*)(out + i + 4) = z;
    } else {
        float (*Ts)[65] = (float(*)[65])smem;
        const int wb = b - 1025;
        const float* src; u16* dst; int K, N, tb;
        if (wb < 4096) { src = W13; dst = W13t; K = NH; N = N13; tb = wb; }
        else           { src = W2;  dst = W2t;  K = NI; N = NH;  tb = wb - 4096; }
        const int ktiles = K >> 6, ntiles = N >> 6;
        const int tpe = ktiles * ntiles;
        const int e = tb / tpe;
        const int rem = tb - e * tpe;
        const int kt = rem / ntiles, nt = rem - (rem / ntiles) * ntiles;
        const float* sb = src + ((size_t)e * K + (size_t)kt * 64) * N + nt * 64;
        #pragma unroll
        for (int i = 0; i < 4; i++) {
            const int idx = tid + i * 256;
            const int r = idx >> 4, c = (idx & 15) << 2;
            const float4 v = *(const float4*)(sb + (size_t)r * N + c);
            Ts[r][c + 0] = v.x; Ts[r][c + 1] = v.y;
            Ts[r][c + 2] = v.z; Ts[r][c + 3] = v.w;
        }
        __syncthreads();
        u16* db = dst + ((size_t)e * N + (size_t)nt * 64) * K + kt * 64;
        #pragma unroll
        for (int i = 0; i < 2; i++) {
            const int u = tid + i * 256;
            const int n = u >> 3, k8 = (u & 7) << 3;
            uint4 o;
            o.x = f2bf(Ts[k8 + 0][n]) | ((u32)f2bf(Ts[k8 + 1][n]) << 16);
            o.y = f2bf(Ts[k8 + 2][n]) | ((u32)f2bf(Ts[k8 + 3][n]) << 16);
            o.z = f2bf(Ts[k8 + 4][n]) | ((u32)f2bf(Ts[k8 + 5][n]) << 16);
            o.w = f2bf(Ts[k8 + 6][n]) | ((u32)f2bf(Ts[k8 + 7][n]) << 16);
            *(uint4*)(db + (size_t)n * K + k8) = o;
        }
    }
}

// ===========================================================================
// GEMM1 tile (R6-verified body): act = silu(X.Wg)*X.Wu
// BM=128 x 32 act cols, BK=32, waves 2x2, XOR-swizzle, safe dbuf.
// ===========================================================================
__device__ __forceinline__ void gemm1_tile(
    int tile, char* smem,
    const u16* __restrict__ Xb, const u16* __restrict__ W13t,
    const int* __restrict__ counts, const int* __restrict__ pair_tok,
    u16* __restrict__ act)
{
    __syncthreads();   // smem handoff from previous use (block-uniform path)
    int e, mt, nt, cnt, base;
    if (!find_tile(counts, tile, 128, NI / 32, e, mt, nt, cnt, base)) return;

    u16* As = (u16*)smem;            // 2 bufs x 128x32
    u16* Bs = (u16*)(smem + 16384);  // 2 bufs x 64x32
    const int tid = threadIdx.x;
    const int ct  = nt * 32;

    const int m0 = tid >> 2;
    const int sw16 = (((tid & 3) ^ (m0 & 3)) << 3);
    const int t0 = pair_tok[base + min(mt * 128 + m0, cnt - 1)];
    const int t1 = pair_tok[base + min(mt * 128 + 64 + m0, cnt - 1)];
    const u16* ga0 = Xb + (size_t)t0 * NH + sw16;
    const u16* ga1 = Xb + (size_t)t1 * NH + sw16;
    const int wcol = (m0 < 32) ? (ct + m0) : (NI + ct + m0 - 32);
    const u16* gb = W13t + ((size_t)e * N13 + wcol) * 1024 + sw16;

    const int lane = tid & 63, w = tid >> 6;
    const int quad = lane >> 4, lid = lane & 15;
    const int rw = w >> 1, cw = w & 1;
    const int fsw = (quad ^ (lid & 3)) << 3;
    int aoff[4];
    #pragma unroll
    for (int mi = 0; mi < 4; mi++)
        aoff[mi] = (rw * 64 + mi * 16 + lid) * 32 + fsw;
    const int bgoff = (cw * 16 + lid) * 32 + fsw;
    const int buoff = (32 + cw * 16 + lid) * 32 + fsw;

    f32x4 accg[4] = {};
    f32x4 accu[4] = {};

#define ISSUE1(b, k0)                                             \
    {                                                             \
        async_ld16(&As[(b) * 4096 + tid * 8],         ga0 + (k0));\
        async_ld16(&As[(b) * 4096 + (tid + 256) * 8], ga1 + (k0));\
        async_ld16(&Bs[(b) * 2048 + tid * 8],         gb  + (k0));\
    }
#define COMP1(b)                                                               \
    {                                                                          \
        short8 av[4];                                                          \
        _Pragma("unroll") for (int mi = 0; mi < 4; mi++)                       \
            av[mi] = *(const short8*)&As[(b) * 4096 + aoff[mi]];               \
        const short8 gv = *(const short8*)&Bs[(b) * 2048 + bgoff];             \
        const short8 uv = *(const short8*)&Bs[(b) * 2048 + buoff];             \
        _Pragma("unroll") for (int mi = 0; mi < 4; mi++) {                     \
            accg[mi] = __builtin_amdgcn_mfma_f32_16x16x32_bf16(                \
                av[mi], gv, accg[mi], 0, 0, 0);                                \
            accu[mi] = __builtin_amdgcn_mfma_f32_16x16x32_bf16(                \
                av[mi], uv, accu[mi], 0, 0, 0);                                \
        }                                                                      \
    }

    ISSUE1(0, 0);
    int buf = 0;
    for (int k0 = 32; k0 < NH; k0 += 32) {
        __syncthreads();
        ISSUE1(buf ^ 1, k0);
        COMP1(buf);
        buf ^= 1;
    }
    __syncthreads();
    COMP1(buf);

    const int col = ct + cw * 16 + lid;
    #pragma unroll
    for (int mi = 0; mi < 4; mi++) {
        #pragma unroll
        for (int r = 0; r < 4; r++) {
            const int row = mt * 128 + rw * 64 + mi * 16 + quad * 4 + r;
            if (row < cnt) {
                const float g = accg[mi][r], u = accu[mi][r];
                const float s = g / (1.0f + __expf(-g)) * u;
                act[(size_t)(base + row) * NI + col] = f2bf(s);
            }
        }
    }
#undef ISSUE1
#undef COMP1
}

// ===========================================================================
// GEMM2 tile (R6-verified body): out[tok] += w_p * (act[p] . W2t[e][h])
// BM=64 x BN=64, BK=32, waves 2x2, safe dbuf, atomic combine.
// ===========================================================================
__device__ __forceinline__ void gemm2_tile(
    int tile, char* smem,
    const u16* __restrict__ act, const u16* __restrict__ W2t,
    const int* __restrict__ counts, const int* __restrict__ pair_tok,
    const float* __restrict__ pair_w, float* __restrict__ out)
{
    __syncthreads();
    int e, mt, nt, cnt, base;
    if (!find_tile(counts, tile, 64, NH / 64, e, mt, nt, cnt, base)) return;

    u16* As = (u16*)smem;            // 2 bufs x 64x32
    u16* Bs = (u16*)(smem + 8192);   // 2 bufs x 64x32
    const int tid = threadIdx.x;
    const int ct  = nt * 64;

    const int m0 = tid >> 2;
    const int sw16 = (((tid & 3) ^ (m0 & 3)) << 3);
    const int p0 = base + min(mt * 64 + m0, cnt - 1);
    const u16* ga = act + (size_t)p0 * NI + sw16;
    const u16* gb = W2t + ((size_t)e * 1024 + ct + m0) * 1024 + sw16;

    const int lane = tid & 63, w = tid >> 6;
    const int quad = lane >> 4, lid = lane & 15;
    const int rw = w >> 1, cw = w & 1;
    const int fsw = (quad ^ (lid & 3)) << 3;
    int aoff[2], boff[2];
    #pragma unroll
    for (int mi = 0; mi < 2; mi++)
        aoff[mi] = (rw * 32 + mi * 16 + lid) * 32 + fsw;
    #pragma unroll
    for (int nj = 0; nj < 2; nj++)
        boff[nj] = (cw * 32 + nj * 16 + lid) * 32 + fsw;

    f32x4 acc[2][2] = {};

#define ISSUE2(b, k0)                                      \
    {                                                      \
        async_ld16(&As[(b) * 2048 + tid * 8], ga + (k0));  \
        async_ld16(&Bs[(b) * 2048 + tid * 8], gb + (k0));  \
    }
#define COMP2(b)                                                               \
    {                                                                          \
        short8 av[2], bv[2];                                                   \
        _Pragma("unroll") for (int mi = 0; mi < 2; mi++)                       \
            av[mi] = *(const short8*)&As[(b) * 2048 + aoff[mi]];               \
        _Pragma("unroll") for (int nj = 0; nj < 2; nj++)                       \
            bv[nj] = *(const short8*)&Bs[(b) * 2048 + boff[nj]];               \
        _Pragma("unroll") for (int mi = 0; mi < 2; mi++)                       \
            _Pragma("unroll") for (int nj = 0; nj < 2; nj++)                   \
                acc[mi][nj] = __builtin_amdgcn_mfma_f32_16x16x32_bf16(         \
                    av[mi], bv[nj], acc[mi][nj], 0, 0, 0);                     \
    }

    ISSUE2(0, 0);
    int buf = 0;
    for (int k0 = 32; k0 < NI; k0 += 32) {
        __syncthreads();
        ISSUE2(buf ^ 1, k0);
        COMP2(buf);
        buf ^= 1;
    }
    __syncthreads();
    COMP2(buf);

    #pragma unroll
    for (int mi = 0; mi < 2; mi++) {
        #pragma unroll
        for (int r = 0; r < 4; r++) {
            const int row = mt * 64 + rw * 32 + mi * 16 + quad * 4 + r;
            if (row < cnt) {
                const int p = base + row;
                const int t = pair_tok[p];
                const float wgt = pair_w[p];
                #pragma unroll
                for (int nj = 0; nj < 2; nj++) {
                    const int col = ct + cw * 32 + nj * 16 + lid;
                    atomicAdd(out + (size_t)t * NH + col, wgt * acc[mi][nj][r]);
                }
            }
        }
    }
#undef ISSUE2
#undef COMP2
}

// ===========================================================================
// Single cooperative kernel (grid-stride phases + grid.sync)
// ===========================================================================
__global__ __launch_bounds__(256, 2) void moe_coop(
    const float* X, const float* logits, const float* W13, const float* W2,
    float* out, int* counts, int* pair_tok, float* pair_w,
    u16* Xb, u16* W13t, u16* W2t, u16* act)
{
    __shared__ __align__(16) char smem[24576];
    cg::grid_group grid = cg::this_grid();

    for (int b = blockIdx.x; b < P0_ITEMS; b += gridDim.x) {
        phase0_item(b, smem, X, logits, W13, W2, out,
                    counts, pair_tok, pair_w, Xb, W13t, W2t);
        __syncthreads();
    }
    __threadfence();
    grid.sync();

    for (int t = blockIdx.x; t < G1MAX; t += gridDim.x)
        gemm1_tile(t, smem, Xb, W13t, counts, pair_tok, act);
    __threadfence();
    grid.sync();

    for (int t = blockIdx.x; t < G2MAX; t += gridDim.x)
        gemm2_tile(t, smem, act, W2t, counts, pair_tok, pair_w, out);
}

// ===========================================================================
// Fallback path: same phase bodies, 3 regular launches
// ===========================================================================
__global__ __launch_bounds__(256) void prep_all_kernel(
    const float* X, const float* logits, const float* W13, const float* W2,
    float* out, int* counts, int* pair_tok, float* pair_w,
    u16* Xb, u16* W13t, u16* W2t)
{
    __shared__ __align__(16) char smem[24576];
    phase0_item(blockIdx.x, smem, X, logits, W13, W2, out,
                counts, pair_tok, pair_w, Xb, W13t, W2t);
}

__global__ __launch_bounds__(256, 2) void gemm1_kernel(
    const u16* Xb, const u16* W13t, const int* counts, const int* pair_tok,
    u16* act)
{
    __shared__ __align__(16) char smem[24576];
    gemm1_tile(blockIdx.x, smem, Xb, W13t, counts, pair_tok, act);
}

__global__ __launch_bounds__(256, 2) void gemm2_kernel(
    const u16* act, const u16* W2t, const int* counts, const int* pair_tok,
    const float* pair_w, float* out)
{
    __shared__ __align__(16) char smem[24576];
    gemm2_tile(blockIdx.x, smem, act, W2t, counts, pair_tok, pair_w, out);
}

// ===========================================================================
extern "C" void kernel_launch(void* const* d_in, const int* in_sizes, int n_in,
                              void* d_out, int out_size, void* d_ws, size_t ws_size,
                              hipStream_t stream)
{
    const float* X      = (const float*)d_in[0];
    const float* logits = (const float*)d_in[1];
    const float* W13    = (const float*)d_in[2];
    const float* W2     = (const float*)d_in[3];
    float* out = (float*)d_out;

    char* ws = (char*)d_ws;
    int*   counts   = (int*)(ws + 0);
    int*   pair_tok = (int*)(ws + 256);
    float* pair_w   = (float*)(ws + 256 + 8192);
    u16*   Xb       = (u16*)(ws + 65536);                 // 2 MiB
    u16*   W13t     = (u16*)(ws + 4194304);               // 32 MiB [E][2I][H]
    u16*   W2t      = (u16*)(ws + 4194304 + 33554432);    // 16 MiB [E][H][I]
    u16*   act      = (u16*)(ws + 54525952);              // 4 MiB  [P][I]

    // Try single cooperative launch, sized by queried occupancy.
    hipError_t st = hipErrorUnknown;
    int occ = 0;
    hipError_t oe = hipOccupancyMaxActiveBlocksPerMultiprocessor(
        &occ, (const void*)moe_coop, 256, 0);
    if (oe == hipSuccess && occ >= 1) {
        int grid = occ * 256;
        if (grid > 768) grid = 768;
        void* kargs[] = {
            (void*)&X, (void*)&logits, (void*)&W13, (void*)&W2, (void*)&out,
            (void*)&counts, (void*)&pair_tok, (void*)&pair_w,
            (void*)&Xb, (void*)&W13t, (void*)&W2t, (void*)&act
        };
        st = hipLaunchCooperativeKernel((const void*)moe_coop, dim3(grid),
                                        dim3(256), kargs, 0, stream);
    }
    if (st != hipSuccess) {
        // Fallback: same math, 3 regular launches.
        prep_all_kernel<<<P0_ITEMS, 256, 0, stream>>>(
            X, logits, W13, W2, out, counts, pair_tok, pair_w, Xb, W13t, W2t);
        gemm1_kernel<<<G1MAX, 256, 0, stream>>>(Xb, W13t, counts, pair_tok, act);
        gemm2_kernel<<<G2MAX, 256, 0, stream>>>(act, W2t, counts, pair_tok, pair_w, out);
    }
}

// Round 9
// 178.006 us; speedup vs baseline: 2.5062x; 2.5062x over previous
//
#include <hip/hip_runtime.h>
#include <hip/hip_bf16.h>
#include <stdint.h>

#define NE    8
#define NTOK  1024
#define NH    1024
#define NI    1024
#define N13   2048
#define NPAIR 2048

#define P0_ITEMS 7169   // 1 routing + 512 Xcvt + 512 zero-out + 6144 Wcvt tiles
#define G1MAX    736    // (2048/128 + 7) * (1024/32)
#define G2MAX    624    // (2048/64  + 7) * (1024/64)

typedef __attribute__((ext_vector_type(8))) short short8;
typedef __attribute__((ext_vector_type(4))) float f32x4;
typedef unsigned short u16;
typedef unsigned int   u32;

__device__ __forceinline__ u16 f2bf(float x) {
    union { float f; u32 u; } v; v.f = x;
    return (u16)((v.u + 0x7fffu + ((v.u >> 16) & 1u)) >> 16);
}

__device__ __forceinline__ void async_ld16(u16* lds, const u16* g) {
    __builtin_amdgcn_global_load_lds(
        (const __attribute__((address_space(1))) u32*)g,
        (__attribute__((address_space(3))) u32*)lds, 16, 0, 0);
}

__device__ __forceinline__ bool find_tile(
    const int* __restrict__ counts, int tile, int bm, int ntn,
    int& e_o, int& mt_o, int& nt_o, int& cnt_o, int& base_o)
{
    int base = 0;
    #pragma unroll
    for (int e = 0; e < NE; e++) {
        const int cnt = counts[e];
        const int mtiles = (cnt + bm - 1) / bm;
        const int tiles = mtiles * ntn;
        if (tile < tiles) {
            e_o = e; mt_o = tile / ntn; nt_o = tile - (tile / ntn) * ntn;
            cnt_o = cnt; base_o = base; return true;
        }
        tile -= tiles; base += cnt;
    }
    return false;
}

// ===========================================================================
// Phase 0 (one launch): 0 = routing; 1..512 = X cvt; 513..1024 = zero out;
// 1025..7168 = weight transpose+cvt tiles (4096 W13 + 2048 W2)
// ===========================================================================
__global__ __launch_bounds__(256) void prep_all_kernel(
    const float* __restrict__ X, const float* __restrict__ logits,
    const float* __restrict__ W13, const float* __restrict__ W2,
    float* __restrict__ out, int* __restrict__ counts,
    int* __restrict__ pair_tok, float* __restrict__ pair_w,
    u16* __restrict__ Xb, u16* __restrict__ W13t, u16* __restrict__ W2t)
{
    __shared__ __align__(16) float Ts[64][65];
    const int tid = threadIdx.x;
    const int b = blockIdx.x;

    if (b == 0) {
        int* s_cnt  = (int*)&Ts[0][0];
        int* s_base = s_cnt + NE;
        if (tid < NE) s_cnt[tid] = 0;
        __syncthreads();
        int eA[4][2]; int slotA[4][2]; float wA[4][2];
        #pragma unroll
        for (int i = 0; i < 4; i++) {
            const int t = tid * 4 + i;
            float l[NE];
            #pragma unroll
            for (int e = 0; e < NE; e++) l[e] = logits[t * NE + e];
            int i0 = 0;
            #pragma unroll
            for (int e = 1; e < NE; e++) if (l[e] > l[i0]) i0 = e;
            int i1 = -1;
            #pragma unroll
            for (int e = 0; e < NE; e++) {
                if (e == i0) continue;
                if (i1 < 0 || l[e] > l[i1]) i1 = e;
            }
            const float e10 = __expf(l[i1] - l[i0]);
            const float inv = 1.0f / (1.0f + e10);
            eA[i][0] = i0; eA[i][1] = i1;
            wA[i][0] = inv; wA[i][1] = e10 * inv;
            slotA[i][0] = atomicAdd(&s_cnt[i0], 1);
            slotA[i][1] = atomicAdd(&s_cnt[i1], 1);
        }
        __syncthreads();
        if (tid == 0) {
            int acc = 0;
            #pragma unroll
            for (int e = 0; e < NE; e++) { s_base[e] = acc; acc += s_cnt[e]; }
        }
        __syncthreads();
        if (tid < NE) counts[tid] = s_cnt[tid];
        #pragma unroll
        for (int i = 0; i < 4; i++) {
            const int t = tid * 4 + i;
            #pragma unroll
            for (int k = 0; k < 2; k++) {
                const int p = s_base[eA[i][k]] + slotA[i][k];
                pair_tok[p] = t;
                pair_w[p]   = wA[i][k];
            }
        }
    } else if (b <= 512) {
        const int i = (b - 1) * 256 + tid;
        const float4* s = (const float4*)X;
        const float4 a = s[2 * i], c = s[2 * i + 1];
        uint4 o;
        o.x = f2bf(a.x) | ((u32)f2bf(a.y) << 16);
        o.y = f2bf(a.z) | ((u32)f2bf(a.w) << 16);
        o.z = f2bf(c.x) | ((u32)f2bf(c.y) << 16);
        o.w = f2bf(c.z) | ((u32)f2bf(c.w) << 16);
        *(uint4*)(Xb + (size_t)i * 8) = o;
    } else if (b <= 1024) {
        const int i = ((b - 513) * 256 + tid) * 8;
        const float4 z = make_float4(0.f, 0.f, 0.f, 0.f);
        *(float4*)(out + i)     = z;
        *(float4*)(out + i + 4) = z;
    } else {
        const int wb = b - 1025;
        const float* src; u16* dst; int K, N, tb;
        if (wb < 4096) { src = W13; dst = W13t; K = NH; N = N13; tb = wb; }
        else           { src = W2;  dst = W2t;  K = NI; N = NH;  tb = wb - 4096; }
        const int ktiles = K >> 6, ntiles = N >> 6;
        const int tpe = ktiles * ntiles;
        const int e = tb / tpe;
        const int rem = tb - e * tpe;
        const int kt = rem / ntiles, nt = rem - (rem / ntiles) * ntiles;
        const float* sb = src + ((size_t)e * K + (size_t)kt * 64) * N + nt * 64;
        #pragma unroll
        for (int i = 0; i < 4; i++) {
            const int idx = tid + i * 256;
            const int r = idx >> 4, c = (idx & 15) << 2;
            const float4 v = *(const float4*)(sb + (size_t)r * N + c);
            Ts[r][c + 0] = v.x; Ts[r][c + 1] = v.y;
            Ts[r][c + 2] = v.z; Ts[r][c + 3] = v.w;
        }
        __syncthreads();
        u16* db = dst + ((size_t)e * N + (size_t)nt * 64) * K + kt * 64;
        #pragma unroll
        for (int i = 0; i < 2; i++) {
            const int u = tid + i * 256;
            const int n = u >> 3, k8 = (u & 7) << 3;
            uint4 o;
            o.x = f2bf(Ts[k8 + 0][n]) | ((u32)f2bf(Ts[k8 + 1][n]) << 16);
            o.y = f2bf(Ts[k8 + 2][n]) | ((u32)f2bf(Ts[k8 + 3][n]) << 16);
            o.z = f2bf(Ts[k8 + 4][n]) | ((u32)f2bf(Ts[k8 + 5][n]) << 16);
            o.w = f2bf(Ts[k8 + 6][n]) | ((u32)f2bf(Ts[k8 + 7][n]) << 16);
            *(uint4*)(db + (size_t)n * K + k8) = o;
        }
    }
}

// ===========================================================================
// GEMM1 (R6-verified): act = silu(X.Wg)*X.Wu
// BM=128 x 32 act cols (64 wcols), BK=32, waves 2x2, XOR-swizzle, safe dbuf.
// ===========================================================================
__global__ __launch_bounds__(256, 2) void gemm1_kernel(
    const u16* __restrict__ Xb, const u16* __restrict__ W13t,
    const int* __restrict__ counts, const int* __restrict__ pair_tok,
    u16* __restrict__ act)
{
    int e, mt, nt, cnt, base;
    if (!find_tile(counts, blockIdx.x, 128, NI / 32, e, mt, nt, cnt, base)) return;

    __shared__ u16 As[2][128 * 32];
    __shared__ u16 Bs[2][64 * 32];

    const int tid = threadIdx.x;
    const int ct  = nt * 32;

    const int m0 = tid >> 2;
    const int sw16 = (((tid & 3) ^ (m0 & 3)) << 3);
    const int t0 = pair_tok[base + min(mt * 128 + m0, cnt - 1)];
    const int t1 = pair_tok[base + min(mt * 128 + 64 + m0, cnt - 1)];
    const u16* ga0 = Xb + (size_t)t0 * NH + sw16;
    const u16* ga1 = Xb + (size_t)t1 * NH + sw16;
    const int wcol = (m0 < 32) ? (ct + m0) : (NI + ct + m0 - 32);
    const u16* gb = W13t + ((size_t)e * N13 + wcol) * 1024 + sw16;

    const int lane = tid & 63, w = tid >> 6;
    const int quad = lane >> 4, lid = lane & 15;
    const int rw = w >> 1, cw = w & 1;
    const int fsw = (quad ^ (lid & 3)) << 3;
    int aoff[4];
    #pragma unroll
    for (int mi = 0; mi < 4; mi++)
        aoff[mi] = (rw * 64 + mi * 16 + lid) * 32 + fsw;
    const int bgoff = (cw * 16 + lid) * 32 + fsw;
    const int buoff = (32 + cw * 16 + lid) * 32 + fsw;

    f32x4 accg[4] = {};
    f32x4 accu[4] = {};

#define ISSUE1(b, k0)                                        \
    {                                                        \
        async_ld16(&As[b][tid * 8],         ga0 + (k0));     \
        async_ld16(&As[b][(tid + 256) * 8], ga1 + (k0));     \
        async_ld16(&Bs[b][tid * 8],         gb  + (k0));     \
    }
#define COMP1(b)                                                               \
    {                                                                          \
        short8 av[4];                                                          \
        _Pragma("unroll") for (int mi = 0; mi < 4; mi++)                       \
            av[mi] = *(const short8*)&As[b][aoff[mi]];                         \
        const short8 gv = *(const short8*)&Bs[b][bgoff];                       \
        const short8 uv = *(const short8*)&Bs[b][buoff];                       \
        _Pragma("unroll") for (int mi = 0; mi < 4; mi++) {                     \
            accg[mi] = __builtin_amdgcn_mfma_f32_16x16x32_bf16(                \
                av[mi], gv, accg[mi], 0, 0, 0);                                \
            accu[mi] = __builtin_amdgcn_mfma_f32_16x16x32_bf16(                \
                av[mi], uv, accu[mi], 0, 0, 0);                                \
        }                                                                      \
    }

    ISSUE1(0, 0);
    int buf = 0;
    for (int k0 = 32; k0 < NH; k0 += 32) {
        __syncthreads();
        ISSUE1(buf ^ 1, k0);
        COMP1(buf);
        buf ^= 1;
    }
    __syncthreads();
    COMP1(buf);

    const int col = ct + cw * 16 + lid;
    #pragma unroll
    for (int mi = 0; mi < 4; mi++) {
        #pragma unroll
        for (int r = 0; r < 4; r++) {
            const int row = mt * 128 + rw * 64 + mi * 16 + quad * 4 + r;
            if (row < cnt) {
                const float g = accg[mi][r], u = accu[mi][r];
                const float s = g / (1.0f + __expf(-g)) * u;
                act[(size_t)(base + row) * NI + col] = f2bf(s);
            }
        }
    }
#undef ISSUE1
#undef COMP1
}

// ===========================================================================
// GEMM2 (R6-verified): out[tok] += w_p * (act[p] . W2t[e][h])
// BM=64 x BN=64, BK=32, waves 2x2, safe dbuf, atomic combine.
// ===========================================================================
__global__ __launch_bounds__(256, 2) void gemm2_kernel(
    const u16* __restrict__ act, const u16* __restrict__ W2t,
    const int* __restrict__ counts, const int* __restrict__ pair_tok,
    const float* __restrict__ pair_w, float* __restrict__ out)
{
    int e, mt, nt, cnt, base;
    if (!find_tile(counts, blockIdx.x, 64, NH / 64, e, mt, nt, cnt, base)) return;

    __shared__ u16 As[2][64 * 32];
    __shared__ u16 Bs[2][64 * 32];

    const int tid = threadIdx.x;
    const int ct  = nt * 64;

    const int m0 = tid >> 2;
    const int sw16 = (((tid & 3) ^ (m0 & 3)) << 3);
    const int p0 = base + min(mt * 64 + m0, cnt - 1);
    const u16* ga = act + (size_t)p0 * NI + sw16;
    const u16* gb = W2t + ((size_t)e * 1024 + ct + m0) * 1024 + sw16;

    const int lane = tid & 63, w = tid >> 6;
    const int quad = lane >> 4, lid = lane & 15;
    const int rw = w >> 1, cw = w & 1;
    const int fsw = (quad ^ (lid & 3)) << 3;
    int aoff[2], boff[2];
    #pragma unroll
    for (int mi = 0; mi < 2; mi++)
        aoff[mi] = (rw * 32 + mi * 16 + lid) * 32 + fsw;
    #pragma unroll
    for (int nj = 0; nj < 2; nj++)
        boff[nj] = (cw * 32 + nj * 16 + lid) * 32 + fsw;

    f32x4 acc[2][2] = {};

#define ISSUE2(b, k0)                                        \
    {                                                        \
        async_ld16(&As[b][tid * 8], ga + (k0));              \
        async_ld16(&Bs[b][tid * 8], gb + (k0));              \
    }
#define COMP2(b)                                                               \
    {                                                                          \
        short8 av[2], bv[2];                                                   \
        _Pragma("unroll") for (int mi = 0; mi < 2; mi++)                       \
            av[mi] = *(const short8*)&As[b][aoff[mi]];                         \
        _Pragma("unroll") for (int nj = 0; nj < 2; nj++)                       \
            bv[nj] = *(const short8*)&Bs[b][boff[nj]];                         \
        _Pragma("unroll") for (int mi = 0; mi < 2; mi++)                       \
            _Pragma("unroll") for (int nj = 0; nj < 2; nj++)                   \
                acc[mi][nj] = __builtin_amdgcn_mfma_f32_16x16x32_bf16(         \
                    av[mi], bv[nj], acc[mi][nj], 0, 0, 0);                     \
    }

    ISSUE2(0, 0);
    int buf = 0;
    for (int k0 = 32; k0 < NI; k0 += 32) {
        __syncthreads();
        ISSUE2(buf ^ 1, k0);
        COMP2(buf);
        buf ^= 1;
    }
    __syncthreads();
    COMP2(buf);

    #pragma unroll
    for (int mi = 0; mi < 2; mi++) {
        #pragma unroll
        for (int r = 0; r < 4; r++) {
            const int row = mt * 64 + rw * 32 + mi * 16 + quad * 4 + r;
            if (row < cnt) {
                const int p = base + row;
                const int t = pair_tok[p];
                const float wgt = pair_w[p];
                #pragma unroll
                for (int nj = 0; nj < 2; nj++) {
                    const int col = ct + cw * 32 + nj * 16 + lid;
                    atomicAdd(out + (size_t)t * NH + col, wgt * acc[mi][nj][r]);
                }
            }
        }
    }
#undef ISSUE2
#undef COMP2
}

// ===========================================================================
extern "C" void kernel_launch(void* const* d_in, const int* in_sizes, int n_in,
                              void* d_out, int out_size, void* d_ws, size_t ws_size,
                              hipStream_t stream)
{
    const float* X      = (const float*)d_in[0];
    const float* logits = (const float*)d_in[1];
    const float* W13    = (const float*)d_in[2];
    const float* W2     = (const float*)d_in[3];
    float* out = (float*)d_out;

    char* ws = (char*)d_ws;
    int*   counts   = (int*)(ws + 0);
    int*   pair_tok = (int*)(ws + 256);
    float* pair_w   = (float*)(ws + 256 + 8192);
    u16*   Xb       = (u16*)(ws + 65536);                 // 2 MiB
    u16*   W13t     = (u16*)(ws + 4194304);               // 32 MiB [E][2I][H]
    u16*   W2t      = (u16*)(ws + 4194304 + 33554432);    // 16 MiB [E][H][I]
    u16*   act      = (u16*)(ws + 54525952);              // 4 MiB  [P][I]

    prep_all_kernel<<<P0_ITEMS, 256, 0, stream>>>(
        X, logits, W13, W2, out, counts, pair_tok, pair_w, Xb, W13t, W2t);
    gemm1_kernel<<<G1MAX, 256, 0, stream>>>(Xb, W13t, counts, pair_tok, act);
    gemm2_kernel<<<G2MAX, 256, 0, stream>>>(act, W2t, counts, pair_tok, pair_w, out);
}